// Round 9
// baseline (215.433 us; speedup 1.0000x reference)
//
#include <hip/hip_runtime.h>
#include <math.h>

#define C_ 8
#define B_ 4
#define T_ 4096
#define D_ 128
#define NCH 128                              // 32-row global chunks
#define CBTD ((size_t)C_ * B_ * T_ * D_)     // 16777216
#define SFLOATS ((size_t)2 * C_ * B_ * NCH * D_)   // 1M floats = 4 MB

typedef __attribute__((ext_vector_type(8))) short short8;
typedef __attribute__((ext_vector_type(4))) float f32x4;

__device__ __forceinline__ float lam_of(int c) {
  return (float)(1.0 - exp2(-(double)c * (13.0 / 7.0)));
}

__device__ __forceinline__ float decay_pow(float lam, float l2lam, int n) {
  if (n == 0) return 1.0f;
  if (lam == 0.0f) return 0.0f;
  return exp2f((float)n * l2lam);
}

__device__ __forceinline__ unsigned short f2bf(float x) {
  unsigned u = __float_as_uint(x);
  unsigned r = (u + 0x7FFFu + ((u >> 16) & 1u)) >> 16;   // RNE
  return (unsigned short)r;
}

// ---- pre-kernel: W (f32 [dir][c][d][e]) -> bf16 transposed Wt[dir*8+c][e][d]
__global__ __launch_bounds__(256)
void wcvt_kernel(const float* __restrict__ Wf, const float* __restrict__ Wb,
                 unsigned short* __restrict__ Wt) {
  __shared__ unsigned short Tq[128][130];
  const int blk = blockIdx.x;          // dir*8 + c
  const float* src = ((blk & 8) ? Wb : Wf) + (size_t)(blk & 7) * D_ * D_;
  const int tid = threadIdx.x;
  for (int i = 0; i < 16; ++i) {
    int fidx = tid + 256 * i;
    int d = fidx >> 5, e4 = (fidx & 31) * 4;
    float4 v = *(const float4*)(src + (size_t)d * D_ + e4);
    Tq[e4 + 0][d] = f2bf(v.x);
    Tq[e4 + 1][d] = f2bf(v.y);
    Tq[e4 + 2][d] = f2bf(v.z);
    Tq[e4 + 3][d] = f2bf(v.w);
  }
  __syncthreads();
  unsigned short* dst = Wt + (size_t)blk * D_ * D_;
  for (int i = 0; i < 8; ++i) {
    int fidx = tid + 256 * i;
    int e = fidx >> 4, d8 = (fidx & 15) * 8;
    unsigned short tmp[8];
    #pragma unroll
    for (int q = 0; q < 8; ++q) tmp[q] = Tq[e][d8 + q];
    #pragma unroll
    for (int q = 0; q < 8; ++q) dst[(size_t)e * D_ + d8 + q] = tmp[q];
  }
}

// ---- Phase A: 128-step blocks, 4 pipelined 32-row sub-tiles, both dirs
__global__ __launch_bounds__(256, 4)
void gate_mfma_kernel(const float* __restrict__ z,
                      const unsigned short* __restrict__ Wt,
                      const float* __restrict__ bf, const float* __restrict__ bb,
                      float* __restrict__ out, float* __restrict__ S) {
  __shared__ float zb[2][32 * 128];    // 2 x 16 KB, XOR-swizzled (slot ^= row&7)
  __shared__ float term[2][8][128];    // 8 KB group terminals -> carries

  const int bi = blockIdx.x;           // (c*4 + b)*32 + bc
  const int bc = bi & 31;
  const int b = (bi >> 5) & 3;
  const int c = bi >> 7;
  const int tid = threadIdx.x;
  const int lane = tid & 63;
  const int w = tid >> 6;              // waves 0,1 -> dir0 ; 2,3 -> dir1
  const int wdir = w >> 1;
  const int l15 = lane & 15;
  const int l4 = lane >> 4;
  const int rowA = (w & 1) * 16 + l15; // MFMA A row (sub-tile local)
  const int rowE = (w & 1) * 16 + l4 * 4;  // C-frag row base

  const float lam = lam_of(c);
  float lp[5];
  lp[0] = 1.f;
  #pragma unroll
  for (int i = 1; i < 5; ++i) lp[i] = lp[i - 1] * lam;

  const float* zseq = z + (size_t)(c * B_ + b) * T_ * D_;
  const int t0 = bc * 128;

  const unsigned short* wt = Wt + (size_t)(wdir * 8 + c) * D_ * D_;
  const float* bias = (wdir ? bb : bf) + (size_t)c * D_;

  // prologue: stage tile 0 (swizzled)
  {
    const float* zt = zseq + (size_t)t0 * D_;
    f32x4 pf[4];
    #pragma unroll
    for (int j = 0; j < 4; ++j) {
      int fidx = tid + 256 * j;
      int row = fidx >> 5, q = fidx & 31;
      pf[j] = *(const f32x4*)(zt + row * 128 + q * 4);
    }
    #pragma unroll
    for (int j = 0; j < 4; ++j) {
      int fidx = tid + 256 * j;
      int row = fidx >> 5, q = fidx & 31;
      *(f32x4*)((char*)&zb[0][0] + row * 512 + ((q ^ (row & 7)) << 4)) = pf[j];
    }
  }
  __syncthreads();

  #pragma unroll
  for (int i = 0; i < 4; ++i) {
    const int curb = i & 1;
    // 1. T14 prefetch: issue next tile's global loads now, consume after bar(A)
    f32x4 pf[4];
    if (i < 3) {
      const float* zt = zseq + (size_t)(t0 + (i + 1) * 32) * D_;
      #pragma unroll
      for (int j = 0; j < 4; ++j) {
        int fidx = tid + 256 * j;
        int row = fidx >> 5, q = fidx & 31;
        pf[j] = *(const f32x4*)(zt + row * 128 + q * 4);
      }
    }

    // 2. A-fragments from zb[curb] (swizzled slots, conflict-free)
    short8 afrag[4];
    #pragma unroll
    for (int ks = 0; ks < 4; ++ks) {
      int x = ks * 8 + l4 * 2;
      int s0 = x ^ (rowA & 7);
      int s1 = (x + 1) ^ (rowA & 7);
      f32x4 a0 = *(const f32x4*)((const char*)&zb[curb][0] + rowA * 512 + (s0 << 4));
      f32x4 a1 = *(const f32x4*)((const char*)&zb[curb][0] + rowA * 512 + (s1 << 4));
      short8 t;
      t[0] = (short)f2bf(a0.x); t[1] = (short)f2bf(a0.y);
      t[2] = (short)f2bf(a0.z); t[3] = (short)f2bf(a0.w);
      t[4] = (short)f2bf(a1.x); t[5] = (short)f2bf(a1.y);
      t[6] = (short)f2bf(a1.z); t[7] = (short)f2bf(a1.w);
      afrag[ks] = t;
    }

    // 3. GEMM for this wave's dir (16 rows x 128 cols x K=128)
    f32x4 acc[8];
    #pragma unroll
    for (int f = 0; f < 8; ++f) acc[f] = (f32x4){0.f, 0.f, 0.f, 0.f};
    #pragma unroll
    for (int f = 0; f < 8; ++f) {
      const unsigned short* wb_ = wt + (size_t)(f * 16 + l15) * D_ + l4 * 8;
      #pragma unroll
      for (int ks = 0; ks < 4; ++ks) {
        short8 bfr = *(const short8*)(wb_ + ks * 32);
        acc[f] = __builtin_amdgcn_mfma_f32_16x16x32_bf16(afrag[ks], bfr, acc[f], 0, 0, 0);
      }
    }

    // 4. epilogue: sigmoid * z (z from LDS), 4-step register scan, terminals
    #pragma unroll
    for (int f = 0; f < 8; ++f) {
      const int col = f * 16 + l15;
      const float bcol = bias[col];
      float vv[4];
      #pragma unroll
      for (int r = 0; r < 4; ++r) {
        const int row = rowE + r;
        const int slot = (col >> 2) ^ (row & 7);
        const float zv = *(const float*)((const char*)&zb[curb][0] +
                          row * 512 + (slot << 4) + (col & 3) * 4);
        const float g = 1.0f / (1.0f + __expf(-(acc[f][r] + bcol)));
        vv[r] = g * zv;
      }
      float h = 0.f;
      if (wdir == 0) {
        #pragma unroll
        for (int r = 0; r < 4; ++r) { h = fmaf(lam, h, vv[r]); acc[f][r] = h; }
      } else {
        #pragma unroll
        for (int r = 3; r >= 0; --r) { h = fmaf(lam, h, vv[r]); acc[f][r] = h; }
      }
      term[wdir][(w & 1) * 4 + l4][col] = (wdir == 0) ? acc[f][3] : acc[f][0];
    }
    __syncthreads();   // A: terminals ready; all z-reads of zb[curb] done

    // 5. A-B window: dual 8-group prefix + S; h0 writeback; stage prefetched tile
    {
      const int d = tid >> 7;
      const int col = tid & 127;
      float p = 0.f;
      const float l4p = lp[4];
      if (d == 0) {
        #pragma unroll
        for (int g = 0; g < 8; ++g) { float t = term[0][g][col]; term[0][g][col] = p; p = fmaf(l4p, p, t); }
      } else {
        #pragma unroll
        for (int g = 7; g >= 0; --g) { float t = term[1][g][col]; term[1][g][col] = p; p = fmaf(l4p, p, t); }
      }
      S[(((size_t)(d * C_ + c) * B_ + b) * NCH + (bc * 4 + i)) * D_ + col] = p;
    }
    if (wdir == 0) {   // dir0 local_h -> zb[curb] (z is dead)
      #pragma unroll
      for (int f = 0; f < 8; ++f) {
        const int col = f * 16 + l15;
        #pragma unroll
        for (int r = 0; r < 4; ++r) {
          const int row = rowE + r;
          const int slot = (col >> 2) ^ (row & 7);
          *(float*)((char*)&zb[curb][0] + row * 512 + (slot << 4) + (col & 3) * 4) = acc[f][r];
        }
      }
    }
    if (i < 3) {       // stage next tile into the other buffer
      #pragma unroll
      for (int j = 0; j < 4; ++j) {
        int fidx = tid + 256 * j;
        int row = fidx >> 5, q = fidx & 31;
        *(f32x4*)((char*)&zb[curb ^ 1][0] + row * 512 + ((q ^ (row & 7)) << 4)) = pf[j];
      }
    }
    __syncthreads();   // B: carries + h0 + next tile all visible

    // 6. stores: dir0 coalesced (carry-fused) from LDS; dir1 scattered from regs
    float* dst0 = out + ((size_t)(c * B_ + b) * T_ + t0 + i * 32) * D_;
    #pragma unroll
    for (int j = 0; j < 4; ++j) {
      int fidx = tid + 256 * j;
      int row = fidx >> 5, q = fidx & 31;
      f32x4 hv = *(const f32x4*)((const char*)&zb[curb][0] + row * 512 + ((q ^ (row & 7)) << 4));
      const f32x4 cv = *(const f32x4*)&term[0][row >> 2][q * 4];
      const float dec = lp[(row & 3) + 1];
      hv.x = fmaf(dec, cv.x, hv.x);
      hv.y = fmaf(dec, cv.y, hv.y);
      hv.z = fmaf(dec, cv.z, hv.z);
      hv.w = fmaf(dec, cv.w, hv.w);
      __builtin_nontemporal_store(hv, (f32x4*)(dst0 + (size_t)row * D_ + q * 4));
    }
    if (wdir == 1) {
      float* dst1 = out + CBTD + ((size_t)(c * B_ + b) * T_ + t0 + i * 32) * D_;
      #pragma unroll
      for (int f = 0; f < 8; ++f) {
        const int col = f * 16 + l15;
        const float carry = term[1][(w & 1) * 4 + l4][col];
        #pragma unroll
        for (int r = 0; r < 4; ++r) {
          const float hv = fmaf(lp[4 - r], carry, acc[f][r]);
          __builtin_nontemporal_store(hv, dst1 + (size_t)(rowE + r) * D_ + col);
        }
      }
    }
  }
}

// ---- Phase B: in-place carry prefix across 128 chunks (S[k] := carry-in)
__global__ __launch_bounds__(128)
void prefix_kernel(float* __restrict__ S) {
  const int bi = blockIdx.x;        // (dir, c, b)
  const int dir = bi >> 5;
  const int c = (bi >> 2) & 7;
  const int b = bi & 3;
  const int e = threadIdx.x;
  const float lam = lam_of(c);
  const float l2lam = (lam > 0.f) ? log2f(lam) : 0.f;
  const float lamL = decay_pow(lam, l2lam, 32);
  float* base = S + ((size_t)(dir * C_ + c) * B_ + b) * NCH * D_ + e;
  float cin = 0.f;
  if (dir == 0) {
    for (int k = 0; k < NCH; ++k) {
      float s = base[(size_t)k * D_];
      base[(size_t)k * D_] = cin;
      cin = fmaf(lamL, cin, s);
    }
  } else {
    for (int k = NCH - 1; k >= 0; --k) {
      float s = base[(size_t)k * D_];
      base[(size_t)k * D_] = cin;
      cin = fmaf(lamL, cin, s);
    }
  }
}

// ---- Phase C: elementwise carry application over 32-row chunks (c=0 skipped)
__global__ __launch_bounds__(128)
void apply_kernel(float* __restrict__ out, const float* __restrict__ S) {
  const int bi = blockIdx.x;          // ((dir*C + c)*B + b)*NCH + k
  const int k = bi & (NCH - 1);
  const int rest = bi >> 7;
  const int b = rest & 3;
  const int c = (rest >> 2) & 7;
  const int dir = rest >> 5;
  if (c == 0) return;                 // lam=0 -> carry always 0
  const float lam = lam_of(c);
  const float l2lam = log2f(lam);
  const int tid = threadIdx.x;
  const int col4 = (tid & 31) * 4;

  const f32x4 carry = *(const f32x4*)
      (S + (((size_t)(dir * C_ + c) * B_ + b) * NCH + k) * D_ + col4);
  float* base = out + (size_t)dir * CBTD +
                ((size_t)(c * B_ + b) * T_ + k * 32) * D_;
  #pragma unroll
  for (int j = 0; j < 8; ++j) {
    const int row = (tid >> 5) + j * 4;
    const int dist = (dir == 0) ? (row + 1) : (32 - row);
    const float dec = exp2f(l2lam * (float)dist);
    f32x4* p = (f32x4*)(base + (size_t)row * D_ + col4);
    f32x4 h = __builtin_nontemporal_load(p);
    h.x = fmaf(dec, carry.x, h.x);
    h.y = fmaf(dec, carry.y, h.y);
    h.z = fmaf(dec, carry.z, h.z);
    h.w = fmaf(dec, carry.w, h.w);
    __builtin_nontemporal_store(h, p);
  }
}

extern "C" void kernel_launch(void* const* d_in, const int* in_sizes, int n_in,
                              void* d_out, int out_size, void* d_ws, size_t ws_size,
                              hipStream_t stream) {
  const float* z  = (const float*)d_in[0];
  const float* Wf = (const float*)d_in[1];
  const float* bf = (const float*)d_in[2];
  const float* Wb = (const float*)d_in[3];
  const float* bb = (const float*)d_in[4];
  float* out = (float*)d_out;
  float* S   = (float*)d_ws;                       // 4 MB
  unsigned short* Wt = (unsigned short*)(S + SFLOATS);  // 512 KB bf16

  wcvt_kernel<<<dim3(16), dim3(256), 0, stream>>>(Wf, Wb, Wt);
  gate_mfma_kernel<<<dim3(C_ * B_ * 32), dim3(256), 0, stream>>>(
      z, Wt, bf, bb, out, S);
  prefix_kernel<<<dim3(2 * C_ * B_), dim3(128), 0, stream>>>(S);
  apply_kernel<<<dim3(2 * C_ * B_ * NCH), dim3(128), 0, stream>>>(out, S);
}

// Round 13
// 95.547 us; speedup vs baseline: 2.2547x; 2.2547x over previous
//
#include <hip/hip_runtime.h>
#include <math.h>

#define C_ 8
#define B_ 4
#define T_ 4096
#define D_ 128
#define TT 64
#define NCH (T_ / TT)                       // 64 chunks
#define CBTD ((size_t)C_ * B_ * T_ * D_)    // 16777216
#define SSIZE ((size_t)2 * C_ * B_ * NCH * D_)  // 524288 floats

typedef __attribute__((ext_vector_type(8))) short short8;
typedef __attribute__((ext_vector_type(4))) float f32x4;

__device__ __forceinline__ float lam_of(int c) {
  return (float)(1.0 - exp2(-(double)c * (13.0 / 7.0)));
}

__device__ __forceinline__ float decay_pow(float lam, float l2lam, int n) {
  if (n == 0) return 1.0f;
  if (lam == 0.0f) return 0.0f;
  return exp2f((float)n * l2lam);
}

__device__ __forceinline__ unsigned short f2bf(float x) {
  unsigned u = __float_as_uint(x);
  unsigned r = (u + 0x7FFFu + ((u >> 16) & 1u)) >> 16;   // RNE
  return (unsigned short)r;
}

// ---- pre-kernel: W (f32 [dir][c][d][e]) -> bf16 in MFMA FRAGMENT ORDER:
//   Wt[dir*8+c][(f*4+ks)*64 + lane] = 8 bf16 {W[d][e], d=ks*32+l4*8+j, e=f*16+l15}
//   so a wave's B-frag load is one contiguous 512B block.
__global__ __launch_bounds__(256)
void wcvt_kernel(const float* __restrict__ Wf, const float* __restrict__ Wb,
                 unsigned short* __restrict__ Wt) {
  __shared__ unsigned short Tq[128][130];   // Tq[e][d]
  const int blk = blockIdx.x;          // dir*8 + c
  const float* src = ((blk & 8) ? Wb : Wf) + (size_t)(blk & 7) * D_ * D_;
  const int tid = threadIdx.x;
  for (int i = 0; i < 16; ++i) {
    int fidx = tid + 256 * i;          // 4096 float4 chunks
    int d = fidx >> 5, e4 = (fidx & 31) * 4;
    float4 v = *(const float4*)(src + (size_t)d * D_ + e4);
    Tq[e4 + 0][d] = f2bf(v.x);
    Tq[e4 + 1][d] = f2bf(v.y);
    Tq[e4 + 2][d] = f2bf(v.z);
    Tq[e4 + 3][d] = f2bf(v.w);
  }
  __syncthreads();
  short8* dst = (short8*)(Wt + (size_t)blk * D_ * D_);
  for (int i = 0; i < 8; ++i) {
    int o = tid + 256 * i;             // out chunk 0..2047
    int f = o >> 8, ks = (o >> 6) & 3, l4s = (o >> 4) & 3, l15s = o & 15;
    short8 t;
    #pragma unroll
    for (int j = 0; j < 8; ++j)
      t[j] = (short)Tq[f * 16 + l15s][ks * 32 + l4s * 8 + j];
    dst[o] = t;
  }
}

// ---- Phase A: dir-merged MFMA gate + local scan; fragment-linear B loads
__global__ __launch_bounds__(256)
void gate_mfma_kernel(const float* __restrict__ z,
                      const unsigned short* __restrict__ Wt,
                      const float* __restrict__ bf, const float* __restrict__ bb,
                      float* __restrict__ out, float* __restrict__ S) {
  __shared__ float term[2][16][132];   // both dirs' group terminals (16.9 KB)
  __shared__ float sbuf[64][132];      // store-coalescing buffer (33.8 KB)

  const int bi = blockIdx.x;
  const int tile = bi & (NCH - 1);
  const int b = (bi >> 6) & (B_ - 1);
  const int c = bi >> 8;
  const int tid = threadIdx.x;
  const int lane = tid & 63;
  const int w = tid >> 6;          // wave -> rows w*16..w*16+15
  const int l15 = lane & 15;
  const int l4 = lane >> 4;

  const float lam = lam_of(c);
  float lp[5];                     // lam^0..lam^4
  lp[0] = 1.f;
  #pragma unroll
  for (int i = 1; i < 5; ++i) lp[i] = lp[i - 1] * lam;

  const float* zsrc = z + ((size_t)(c * B_ + b) * T_ + tile * TT) * D_;

  // A-fragments direct from global: lane holds A[m=l15][k=l4*8+j], k-chunk ks*32
  short8 afrag[4];
  const int rowA = w * 16 + l15;
  #pragma unroll
  for (int ks = 0; ks < 4; ++ks) {
    const float* p = zsrc + (size_t)rowA * D_ + ks * 32 + l4 * 8;
    float4 a0 = *(const float4*)p;
    float4 a1 = *(const float4*)(p + 4);
    short8 t;
    t[0] = (short)f2bf(a0.x); t[1] = (short)f2bf(a0.y);
    t[2] = (short)f2bf(a0.z); t[3] = (short)f2bf(a0.w);
    t[4] = (short)f2bf(a1.x); t[5] = (short)f2bf(a1.y);
    t[6] = (short)f2bf(a1.z); t[7] = (short)f2bf(a1.w);
    afrag[ks] = t;
  }

  // epilogue z in C-fragment layout (L1-hot: same 16 rows just fetched)
  float zreg[8][4];
  const int rowE = w * 16 + l4 * 4;
  #pragma unroll
  for (int f = 0; f < 8; ++f)
    #pragma unroll
    for (int r = 0; r < 4; ++r)
      zreg[f][r] = zsrc[(size_t)(rowE + r) * D_ + f * 16 + l15];

  // ---- both dirs' GEMMs in one dependence window (fragment-linear B loads)
  const short8* wf0 = (const short8*)(Wt + (size_t)(0 * 8 + c) * D_ * D_);
  const short8* wf1 = (const short8*)(Wt + (size_t)(1 * 8 + c) * D_ * D_);

  f32x4 acc[2][8];
  #pragma unroll
  for (int d = 0; d < 2; ++d)
    #pragma unroll
    for (int f = 0; f < 8; ++f) acc[d][f] = (f32x4){0.f, 0.f, 0.f, 0.f};

  #pragma unroll
  for (int f = 0; f < 8; ++f) {
    #pragma unroll
    for (int ks = 0; ks < 4; ++ks) {
      short8 b0 = wf0[(f * 4 + ks) * 64 + lane];
      short8 b1 = wf1[(f * 4 + ks) * 64 + lane];
      acc[0][f] = __builtin_amdgcn_mfma_f32_16x16x32_bf16(afrag[ks], b0, acc[0][f], 0, 0, 0);
      acc[1][f] = __builtin_amdgcn_mfma_f32_16x16x32_bf16(afrag[ks], b1, acc[1][f], 0, 0, 0);
    }
  }

  // ---- epilogues: v = sigmoid(logit)*z, 4-step register scan (in-place on acc)
  #pragma unroll
  for (int d = 0; d < 2; ++d) {
    const float* bias = (d ? bb : bf) + (size_t)c * D_;
    #pragma unroll
    for (int f = 0; f < 8; ++f) {
      const float bcol = bias[f * 16 + l15];
      float vv[4];
      #pragma unroll
      for (int r = 0; r < 4; ++r) {
        const float logit = acc[d][f][r] + bcol;
        const float g = 1.0f / (1.0f + __expf(-logit));
        vv[r] = g * zreg[f][r];
      }
      if (d == 0) {
        float h = 0.f;
        #pragma unroll
        for (int r = 0; r < 4; ++r) { h = fmaf(lam, h, vv[r]); acc[d][f][r] = h; }
      } else {
        float h = 0.f;
        #pragma unroll
        for (int r = 3; r >= 0; --r) { h = fmaf(lam, h, vv[r]); acc[d][f][r] = h; }
      }
      term[d][w * 4 + l4][f * 16 + l15] = (d == 0) ? acc[d][f][3] : acc[d][f][0];
    }
  }
  __syncthreads();

  // ---- dual prefix: waves 0-1 handle dir0, waves 2-3 handle dir1
  {
    const int d = tid >> 7;
    const int col = tid & 127;
    float tg[16];
    #pragma unroll
    for (int g = 0; g < 16; ++g) tg[g] = term[d][g][col];
    float p = 0.f;
    const float l4p = lp[4];
    if (d == 0) {
      #pragma unroll
      for (int g = 0; g < 16; ++g) { float t = tg[g]; term[d][g][col] = p; p = fmaf(l4p, p, t); }
    } else {
      #pragma unroll
      for (int g = 15; g >= 0; --g) { float t = tg[g]; term[d][g][col] = p; p = fmaf(l4p, p, t); }
    }
    S[(((size_t)(d * C_ + c) * B_ + b) * NCH + tile) * D_ + col] = p;
  }

  // ---- apply group carry, stage in LDS, store coalesced (nontemporal)
  #pragma unroll
  for (int d = 0; d < 2; ++d) {
    __syncthreads();   // d==0: prefix done; d==1: sbuf readers of d0 done
    #pragma unroll
    for (int f = 0; f < 8; ++f) {
      const int col = f * 16 + l15;
      const float carry = term[d][w * 4 + l4][col];
      #pragma unroll
      for (int r = 0; r < 4; ++r) {
        const float dec = (d == 0) ? lp[r + 1] : lp[4 - r];
        sbuf[rowE + r][col] = fmaf(dec, carry, acc[d][f][r]);
      }
    }
    __syncthreads();
    float* dst = out + (size_t)d * CBTD +
                 ((size_t)(c * B_ + b) * T_ + tile * TT) * D_;
    #pragma unroll
    for (int i = 0; i < 8; ++i) {
      int fidx = tid + 256 * i;        // 2048 float4 = 64 rows x 32 col4
      int row = fidx >> 5, col4 = (fidx & 31) * 4;
      f32x4 v = *(const f32x4*)&sbuf[row][col4];
      __builtin_nontemporal_store(v, (f32x4*)(dst + (size_t)row * D_ + col4));
    }
  }
}

// ---- Phase B: carry prefix across chunks (tiny)
__global__ __launch_bounds__(128)
void prefix_kernel(const float* __restrict__ S, float* __restrict__ Cin) {
  const int bi = blockIdx.x;        // (dir, c, b)
  const int dir = bi >> 5;
  const int c = (bi >> 2) & 7;
  const int b = bi & 3;
  const int e = threadIdx.x;
  const float lam = lam_of(c);
  const float l2lam = (lam > 0.f) ? log2f(lam) : 0.f;
  const float lamL = decay_pow(lam, l2lam, TT);
  const size_t base = ((size_t)(dir * C_ + c) * B_ + b) * NCH * D_ + e;
  float cin = 0.f;
  if (dir == 0) {
    for (int k = 0; k < NCH; ++k) {
      Cin[base + (size_t)k * D_] = cin;
      cin = fmaf(lamL, cin, S[base + (size_t)k * D_]);
    }
  } else {
    for (int k = NCH - 1; k >= 0; --k) {
      Cin[base + (size_t)k * D_] = cin;
      cin = fmaf(lamL, cin, S[base + (size_t)k * D_]);
    }
  }
}

// ---- Phase C: elementwise carry application, h += lam^dist * carry (c=0 skipped)
__global__ __launch_bounds__(256)
void apply_kernel(float* __restrict__ out, const float* __restrict__ Cin) {
  const int bi = blockIdx.x;          // ((dir*C + c)*B + b)*NCH + k
  const int k = bi & (NCH - 1);
  const int b = (bi >> 6) & 3;
  const int c = (bi >> 8) & 7;
  const int dir = bi >> 11;
  if (c == 0) return;                 // lam=0 -> carry always 0
  const float lam = lam_of(c);
  const float l2lam = log2f(lam);
  const int tid = threadIdx.x;
  const int col4 = (tid & 31) * 4;

  const f32x4 carry = *(const f32x4*)
      (Cin + (((size_t)(dir * C_ + c) * B_ + b) * NCH + k) * D_ + col4);
  float* base = out + (size_t)dir * CBTD +
                ((size_t)(c * B_ + b) * T_ + k * TT) * D_;
  #pragma unroll
  for (int i = 0; i < 8; ++i) {
    const int row = (tid >> 5) + i * 8;
    const int dist = (dir == 0) ? (row + 1) : (TT - row);
    const float dec = exp2f(l2lam * (float)dist);
    f32x4* p = (f32x4*)(base + (size_t)row * D_ + col4);
    f32x4 h = __builtin_nontemporal_load(p);
    h.x = fmaf(dec, carry.x, h.x);
    h.y = fmaf(dec, carry.y, h.y);
    h.z = fmaf(dec, carry.z, h.z);
    h.w = fmaf(dec, carry.w, h.w);
    __builtin_nontemporal_store(h, p);
  }
}

extern "C" void kernel_launch(void* const* d_in, const int* in_sizes, int n_in,
                              void* d_out, int out_size, void* d_ws, size_t ws_size,
                              hipStream_t stream) {
  const float* z  = (const float*)d_in[0];
  const float* Wf = (const float*)d_in[1];
  const float* bf = (const float*)d_in[2];
  const float* Wb = (const float*)d_in[3];
  const float* bb = (const float*)d_in[4];
  float* out = (float*)d_out;
  float* S   = (float*)d_ws;                      // 2 MB
  float* Cin = S + SSIZE;                         // 2 MB
  unsigned short* Wt = (unsigned short*)(Cin + SSIZE);  // 512 KB bf16

  wcvt_kernel<<<dim3(16), dim3(256), 0, stream>>>(Wf, Wb, Wt);
  gate_mfma_kernel<<<dim3(C_ * B_ * NCH), dim3(256), 0, stream>>>(
      z, Wt, bf, bb, out, S);
  prefix_kernel<<<dim3(2 * C_ * B_), dim3(128), 0, stream>>>(S, Cin);
  apply_kernel<<<dim3(2 * C_ * B_ * NCH), dim3(256), 0, stream>>>(out, Cin);
}